// Round 4
// baseline (109.841 us; speedup 1.0000x reference)
//
#include <hip/hip_runtime.h>
#include <math.h>

#define EDIM 256
#define LDIM 1024
#define HDIM 8
#define DDIM 32

typedef __attribute__((ext_vector_type(8))) short short8;
typedef __attribute__((ext_vector_type(4))) float f32x4;

__device__ inline unsigned short bf16h(float x) {
    unsigned u = __float_as_uint(x);
    return (unsigned short)((u + 0x7fff + ((u >> 16) & 1)) >> 16);   // RNE
}
__device__ inline float bf16tof(unsigned short h) {
    return __uint_as_float(((unsigned)h) << 16);
}
// native base-2 transcendentals (v_exp_f32: D=2^S0, v_log_f32: D=log2(S0)).
// Inline asm avoids the glibc __exp2f/__log2f reserved-identifier collision.
__device__ inline float exp2fast(float x) {
    float r; asm volatile("v_exp_f32 %0, %1" : "=v"(r) : "v"(x)); return r;
}
__device__ inline float log2fast(float x) {
    float r; asm volatile("v_log_f32 %0, %1" : "=v"(r) : "v"(x)); return r;
}

// base-2 softmax scale: 1/16 (energy/sqrt(E)) * log2(e)
#define SC2 0.09016843880556021f

// ---------------------------------------------------------------------------
// proj_kernel (MFMA): z<3: dst(H,L,D) = X(L,E) @ W(E,E)^T, outputs written as
// SEPARATE hi/lo bf16 short arrays (consumers do zero unpack ALU). 32x32
// tile, 4 waves x one 16x16 frag, BK=64, split-bf16 3-term. z==0 also fuses
// coeff[h][n] = sum_d q[n,h,d]*Wr[h*32+d]. z==3: split Wo into Wohi/Wolo
// for the finale kernel (one elem per thread, 256 blocks).
// ---------------------------------------------------------------------------
__global__ __launch_bounds__(256) void proj_kernel(
    const float* __restrict__ Q, const float* __restrict__ Km, const float* __restrict__ V,
    const float* __restrict__ Wq, const float* __restrict__ Wk, const float* __restrict__ Wv,
    const float* __restrict__ Wr, const float* __restrict__ Wo,
    short* __restrict__ qThi, short* __restrict__ qTlo,
    short* __restrict__ kThi, short* __restrict__ kTlo,
    short* __restrict__ vThi, short* __restrict__ vTlo,
    float* __restrict__ coeff, short* __restrict__ Wohi, short* __restrict__ Wolo)
{
    const int z = blockIdx.z;
    const int tid = threadIdx.x;

    if (z == 3) {   // Wo hi/lo split prep (256 blocks x 256 thr = 65536 elems)
        const int idx = ((blockIdx.y * 32 + blockIdx.x) << 8) + tid;
        const float w = Wo[idx];
        const unsigned short hh = bf16h(w);
        Wohi[idx] = (short)hh;
        Wolo[idx] = (short)bf16h(w - bf16tof(hh));
        return;
    }

    const float* __restrict__ X = (z == 0) ? Q : (z == 1) ? Km : V;
    const float* __restrict__ W = (z == 0) ? Wq : (z == 1) ? Wk : Wv;
    short* __restrict__ dhi     = (z == 0) ? qThi : (z == 1) ? kThi : vThi;
    short* __restrict__ dlo     = (z == 0) ? qTlo : (z == 1) ? kTlo : vTlo;

    const int n0 = blockIdx.x * 32;
    const int o0 = blockIdx.y * 32;   // one head: o0 = h*32
    const int wave = tid >> 6, lane = tid & 63;
    const int n = lane & 15, quad = lane >> 4;
    const int rh = wave & 1, oh = wave >> 1;   // wave's row-half / col-half

    // staging role: K-slice s (32 wide), row r (0..31), k-quad qd (8 elems)
    const int s    = tid >> 7;
    const int r    = (tid >> 2) & 31;
    const int qd   = tid & 3;
    const int half = r >> 4;
    const int fl8  = ((r & 15) | (qd << 4)) * 8;   // frag-lane * 8

    __shared__ short Xhi[2][2][512], Xlo[2][2][512];   // [slice][row-half][lane*8]
    __shared__ short Whi[2][2][512], Wlo[2][2][512];
    __shared__ float cpart[2][2][16];

    const float* xp = X + (n0 + r) * EDIM + s * 32 + qd * 8;
    const float* wp = W + (o0 + r) * EDIM + s * 32 + qd * 8;

    float4 xa0 = *(const float4*)xp, xa1 = *(const float4*)(xp + 4);
    float4 wa0 = *(const float4*)wp, wa1 = *(const float4*)(wp + 4);

    f32x4 acc = {0.f, 0.f, 0.f, 0.f};

    for (int kb = 0; kb < EDIM; kb += 64) {
        __syncthreads();   // previous compute done, LDS free
        {
            float xv[8] = {xa0.x,xa0.y,xa0.z,xa0.w, xa1.x,xa1.y,xa1.z,xa1.w};
            float wv[8] = {wa0.x,wa0.y,wa0.z,wa0.w, wa1.x,wa1.y,wa1.z,wa1.w};
            short8 xh, xl, wh, wl;
            #pragma unroll
            for (int j = 0; j < 8; ++j) {
                unsigned short xhh = bf16h(xv[j]);
                unsigned short whh = bf16h(wv[j]);
                xh[j] = (short)xhh; xl[j] = (short)bf16h(xv[j] - bf16tof(xhh));
                wh[j] = (short)whh; wl[j] = (short)bf16h(wv[j] - bf16tof(whh));
            }
            *(short8*)&Xhi[s][half][fl8] = xh;
            *(short8*)&Xlo[s][half][fl8] = xl;
            *(short8*)&Whi[s][half][fl8] = wh;
            *(short8*)&Wlo[s][half][fl8] = wl;
        }
        float4 xn0, xn1, wn0, wn1;
        if (kb + 64 < EDIM) {
            xn0 = *(const float4*)(xp + kb + 64); xn1 = *(const float4*)(xp + kb + 68);
            wn0 = *(const float4*)(wp + kb + 64); wn1 = *(const float4*)(wp + kb + 68);
        }
        __syncthreads();   // staged
        #pragma unroll
        for (int ss = 0; ss < 2; ++ss) {
            short8 ah = *(const short8*)&Xhi[ss][rh][lane*8];
            short8 al = *(const short8*)&Xlo[ss][rh][lane*8];
            short8 bh = *(const short8*)&Whi[ss][oh][lane*8];
            short8 bl = *(const short8*)&Wlo[ss][oh][lane*8];
            acc = __builtin_amdgcn_mfma_f32_16x16x32_bf16(al, bh, acc, 0, 0, 0);
            acc = __builtin_amdgcn_mfma_f32_16x16x32_bf16(ah, bl, acc, 0, 0, 0);
            acc = __builtin_amdgcn_mfma_f32_16x16x32_bf16(ah, bh, acc, 0, 0, 0);
        }
        xa0 = xn0; xa1 = xn1; wa0 = wn0; wa1 = wn1;
    }

    // epilogue: D layout row = rh*16 + 4*quad + i, col = oh*16 + n.
    const int h  = o0 >> 5;
    const int og = oh * 16 + n;
    #pragma unroll
    for (int i = 0; i < 4; ++i) {
        const int row = rh * 16 + 4 * quad + i;
        const unsigned short hh = bf16h(acc[i]);
        dhi[(h * LDIM + n0 + row) * DDIM + og] = (short)hh;
        dlo[(h * LDIM + n0 + row) * DDIM + og] = (short)bf16h(acc[i] - bf16tof(hh));
    }

    if (z == 0) {   // coeff[h][n] = sum over d (all 32 cols = 2 waves x 16 lanes)
        const float wr = Wr[o0 + og];
        #pragma unroll
        for (int i = 0; i < 4; ++i) {
            float c = acc[i] * wr;
            c += __shfl_xor(c, 1, 64);
            c += __shfl_xor(c, 2, 64);
            c += __shfl_xor(c, 4, 64);
            c += __shfl_xor(c, 8, 64);
            if (n == 0) cpart[rh][oh][4*quad + i] = c;
        }
        __syncthreads();
        if (tid < 32)
            coeff[h * LDIM + n0 + tid] = cpart[tid >> 4][0][tid & 15]
                                       + cpart[tid >> 4][1][tid & 15];
    }
}

// ---------------------------------------------------------------------------
// attn_kernel: flash attention, QK^T and PV on MFMA (split-bf16 3-term).
// All operands arrive/live as SEPARATE hi/lo short arrays: K staging is a
// register passthrough (0 ALU), V/P LDS reads are direct short8 frags.
// Softmax is base-2 (v_exp_f32/v_log_f32 natively compute 2^x/log2; log2e
// folded into SC2; cq's ln2 factors cancel exactly). 2 barriers/tile,
// in-register alpha rescale. Block: 64 q-rows, 4 waves. Grid (16, H, P).
// ---------------------------------------------------------------------------
__global__ __launch_bounds__(256, 4) void attn_kernel(
    const short* __restrict__ qThi, const short* __restrict__ qTlo,
    const short* __restrict__ kThi, const short* __restrict__ kTlo,
    const short* __restrict__ vThi, const short* __restrict__ vTlo,
    const float* __restrict__ coeff, const float* __restrict__ pos,
    float* __restrict__ Op, float* __restrict__ Mp, float* __restrict__ Lp, int nkt)
{
    const int h   = blockIdx.y;
    const int q0  = blockIdx.x * 64;
    const int p   = blockIdx.z;
    const int kt0 = p * nkt * 64;
    const int tid  = threadIdx.x;
    const int wave = tid >> 6;
    const int lane = tid & 63;
    const int n    = lane & 15;
    const int quad = lane >> 4;
    const int qs0  = wave * 16;

    __shared__ __align__(16) short khi[4*64*8];      // QK^T B-frags (hi)
    __shared__ __align__(16) short klo[4*64*8];      // QK^T B-frags (lo)
    __shared__ __align__(16) short vs_hi[32][72];    // vs[d][c] (pitch 144B: 16B-aligned rows)
    __shared__ __align__(16) short vs_lo[32][72];
    __shared__ __align__(16) short pa_hi[64][72];    // P[q][c]
    __shared__ __align__(16) short pa_lo[64][72];
    __shared__ float pk[64];

    // ---- Q fragments (A layout): direct short8 loads, zero unpack ----
    const short8 qhi = *(const short8*)(qThi + (h*LDIM + q0 + qs0 + n) * DDIM + quad*8);
    const short8 qlo = *(const short8*)(qTlo + (h*LDIM + q0 + qs0 + n) * DDIM + quad*8);

    float pq[4], cq[4];
    #pragma unroll
    for (int i = 0; i < 4; ++i) {
        const int r = q0 + qs0 + 4*quad + i;
        pq[i] = pos[r];
        cq[i] = coeff[h*LDIM + r] * 0.0625f;
    }

    float m[4], l[4];
    #pragma unroll
    for (int i = 0; i < 4; ++i) { m[i] = -INFINITY; l[i] = 0.f; }

    // O accumulators in MFMA C/D layout: row = 4*quad+i, col d = dt*16 + n
    f32x4 of0 = {0.f,0.f,0.f,0.f}, of1 = {0.f,0.f,0.f,0.f};

    const int cS = tid >> 2;           // k-row 0..63
    const int dq = tid & 3;            // d-chunk 0..3 (8 elems each)
    const int lane2 = (cS & 15) | (dq << 4);
    const int gS = cS >> 4;

    // preload tile 0
    short8 khi_c, klo_c, vhi_c, vlo_c; float pkc = 0.f;
    {
        const int off = (h*LDIM + kt0 + cS) * DDIM + dq*8;
        khi_c = *(const short8*)(kThi + off);
        klo_c = *(const short8*)(kTlo + off);
        vhi_c = *(const short8*)(vThi + off);
        vlo_c = *(const short8*)(vTlo + off);
        if (tid < 64) pkc = pos[kt0 + tid];
    }

    for (int t = 0; t < nkt; ++t) {
        __syncthreads();   // (A) prev tile's consumers done

        // stage K (register passthrough), V (transpose scatter), pk
        *((short8*)&khi[(gS*64 + lane2)*8]) = khi_c;
        *((short8*)&klo[(gS*64 + lane2)*8]) = klo_c;
        #pragma unroll
        for (int j = 0; j < 8; ++j) {
            vs_hi[dq*8 + j][cS] = vhi_c[j];
            vs_lo[dq*8 + j][cS] = vlo_c[j];
        }
        if (tid < 64) pk[tid] = pkc;

        // prefetch next tile (overlaps with compute below)
        short8 khi_n, klo_n, vhi_n, vlo_n; float pkn = 0.f;
        if (t + 1 < nkt) {
            const int off = (h*LDIM + kt0 + (t+1)*64 + cS) * DDIM + dq*8;
            khi_n = *(const short8*)(kThi + off);
            klo_n = *(const short8*)(kTlo + off);
            vhi_n = *(const short8*)(vThi + off);
            vlo_n = *(const short8*)(vTlo + off);
            if (tid < 64) pkn = pos[kt0 + (t+1)*64 + tid];
        }
        __syncthreads();   // (B) staging visible

        // ---- S = QK^T via 3-term split-bf16 MFMA, 4 col-tiles ----
        f32x4 Sf[4];
        #pragma unroll
        for (int t4 = 0; t4 < 4; ++t4) {
            short8 bhi = *((const short8*)&khi[(t4*64 + lane)*8]);
            short8 blo = *((const short8*)&klo[(t4*64 + lane)*8]);
            f32x4 acc = {0.f, 0.f, 0.f, 0.f};
            acc = __builtin_amdgcn_mfma_f32_16x16x32_bf16(qlo, bhi, acc, 0, 0, 0);
            acc = __builtin_amdgcn_mfma_f32_16x16x32_bf16(qhi, blo, acc, 0, 0, 0);
            acc = __builtin_amdgcn_mfma_f32_16x16x32_bf16(qhi, bhi, acc, 0, 0, 0);
            Sf[t4] = acc;
        }

        // ---- bias + online softmax, base-2 domain ----
        float ev[4][4];
        float rmax[4] = {-INFINITY, -INFINITY, -INFINITY, -INFINITY};
        #pragma unroll
        for (int t4 = 0; t4 < 4; ++t4) {
            const float pkt = pk[16*t4 + n];
            #pragma unroll
            for (int i = 0; i < 4; ++i) {
                float s = fmaf(Sf[t4][i], SC2, cq[i] * log2fast(fabsf(pq[i] - pkt) + 1.f));
                ev[t4][i] = s;
                rmax[i] = fmaxf(rmax[i], s);
            }
        }
        #pragma unroll
        for (int off = 1; off < 16; off <<= 1)
            #pragma unroll
            for (int i = 0; i < 4; ++i)
                rmax[i] = fmaxf(rmax[i], __shfl_xor(rmax[i], off, 64));

        float al[4], rsum[4];
        #pragma unroll
        for (int i = 0; i < 4; ++i) {
            const float mn = fmaxf(m[i], rmax[i]);
            al[i] = exp2fast(m[i] - mn);
            m[i] = mn;
            rsum[i] = 0.f;
        }
        // exp2, row-sum, write split P (wave-private rows: no barrier needed)
        #pragma unroll
        for (int t4 = 0; t4 < 4; ++t4)
            #pragma unroll
            for (int i = 0; i < 4; ++i) {
                float e = exp2fast(ev[t4][i] - m[i]);
                rsum[i] += e;
                unsigned u = __float_as_uint(e);
                pa_hi[qs0 + 4*quad + i][16*t4 + n] = (short)(u >> 16);
                float r = e - __uint_as_float(u & 0xffff0000u);
                pa_lo[qs0 + 4*quad + i][16*t4 + n] = (short)bf16h(r);
            }
        #pragma unroll
        for (int off = 1; off < 16; off <<= 1)
            #pragma unroll
            for (int i = 0; i < 4; ++i)
                rsum[i] += __shfl_xor(rsum[i], off, 64);
        #pragma unroll
        for (int i = 0; i < 4; ++i) l[i] = l[i]*al[i] + rsum[i];

        // in-register O rescale: O rows (4*quad+i) match al[i] rows exactly
        #pragma unroll
        for (int i = 0; i < 4; ++i) { of0[i] *= al[i]; of1[i] *= al[i]; }

        // ---- PV on MFMA: direct short8 frag reads, zero unpack ----
        #pragma unroll
        for (int ch = 0; ch < 2; ++ch) {
            short8 phi = *(const short8*)&pa_hi[qs0 + n][ch*32 + quad*8];
            short8 plo = *(const short8*)&pa_lo[qs0 + n][ch*32 + quad*8];
            #pragma unroll
            for (int dt = 0; dt < 2; ++dt) {
                short8 vh8 = *(const short8*)&vs_hi[dt*16 + n][ch*32 + quad*8];
                short8 vl8 = *(const short8*)&vs_lo[dt*16 + n][ch*32 + quad*8];
                f32x4& of = dt ? of1 : of0;   // dt is unroll-constant: static
                of = __builtin_amdgcn_mfma_f32_16x16x32_bf16(plo, vh8, of, 0, 0, 0);
                of = __builtin_amdgcn_mfma_f32_16x16x32_bf16(phi, vl8, of, 0, 0, 0);
                of = __builtin_amdgcn_mfma_f32_16x16x32_bf16(phi, vh8, of, 0, 0, 0);
            }
        }

        khi_c = khi_n; klo_c = klo_n; vhi_c = vhi_n; vlo_c = vlo_n; pkc = pkn;
    }

    // epilogue: O is in C/D layout (row 4*quad+i, col dt*16+n)
    const int ph = p * HDIM + h;
    {
        const size_t base = ((size_t)ph * LDIM + q0 + qs0) * DDIM;
        #pragma unroll
        for (int i = 0; i < 4; ++i) {
            Op[base + (size_t)(4*quad + i)*DDIM + n]      = of0[i];
            Op[base + (size_t)(4*quad + i)*DDIM + 16 + n] = of1[i];
        }
    }
    if (n == 0) {
        #pragma unroll
        for (int i = 0; i < 4; ++i) {
            const int r = q0 + qs0 + 4*quad + i;
            Mp[ph*LDIM + r] = m[i];   // base-2 max
            Lp[ph*LDIM + r] = l[i];
        }
    }
}

// ---------------------------------------------------------------------------
// finale_kernel: fused combine + out-projection.
// 128 blocks x 256 thr; block b owns rows n0 = b*8 (M=8) and ALL 256 cols.
// Phase A: A_tile[8][256] = normalized combine of P partials -> split hi/lo
// in LDS. Phase B: out = A @ Wo^T + bo on MFMA (Wo pre-split by proj z=3,
// read straight from L2 as short8 B-frags). D rows 8..15 are don't-care
// (A rows duplicated via n&7); only quad<2 stores.
// ---------------------------------------------------------------------------
__global__ __launch_bounds__(256) void finale_kernel(
    const float* __restrict__ Op, const float* __restrict__ Mp, const float* __restrict__ Lp,
    const short* __restrict__ Wohi, const short* __restrict__ Wolo,
    const float* __restrict__ bo, int P, float* __restrict__ out)
{
    const int n0 = blockIdx.x * 8;
    const int tid = threadIdx.x;

    __shared__ __align__(16) short Ahi[8][264], Alo[8][264];   // pitch 528B (16B-aligned)

    {   // ---- phase A: combine ----
        const int r  = tid >> 5;          // 0..7
        const int c8 = (tid & 31) * 8;    // 0..248
        const int hh = c8 >> 5;
        const int d  = c8 & 31;           // 0,8,16,24
        float mv[8], lv[8];
        float mx = -INFINITY;
        #pragma unroll
        for (int p = 0; p < 8; ++p) if (p < P) {
            mv[p] = Mp[(p*HDIM + hh)*LDIM + n0 + r];
            lv[p] = Lp[(p*HDIM + hh)*LDIM + n0 + r];
            mx = fmaxf(mx, mv[p]);
        }
        float s = 0.f;
        #pragma unroll
        for (int p = 0; p < 8; ++p) if (p < P) {
            float a = exp2fast(mv[p] - mx);   // base-2 m's
            mv[p] = a;
            s += a * lv[p];
        }
        const float inv = 1.f / s;
        float a[8] = {0.f,0.f,0.f,0.f,0.f,0.f,0.f,0.f};
        #pragma unroll
        for (int p = 0; p < 8; ++p) if (p < P) {
            const float sp = mv[p] * inv;
            const float* op = Op + ((size_t)(p*HDIM + hh)*LDIM + n0 + r)*DDIM + d;
            float4 x0 = *(const float4*)op;
            float4 x1 = *(const float4*)(op + 4);
            a[0] += sp*x0.x; a[1] += sp*x0.y; a[2] += sp*x0.z; a[3] += sp*x0.w;
            a[4] += sp*x1.x; a[5] += sp*x1.y; a[6] += sp*x1.z; a[7] += sp*x1.w;
        }
        short8 ah8, al8;
        #pragma unroll
        for (int j = 0; j < 8; ++j) {
            const unsigned short hhh = bf16h(a[j]);
            ah8[j] = (short)hhh;
            al8[j] = (short)bf16h(a[j] - bf16tof(hhh));
        }
        *(short8*)&Ahi[r][c8] = ah8;
        *(short8*)&Alo[r][c8] = al8;
    }
    __syncthreads();

    // ---- phase B: GEMM (M=8 via 16x16 frags, rows 8..15 don't-care) ----
    const int wave = tid >> 6, lane = tid & 63;
    const int n = lane & 15, quad = lane >> 4;
    const int ow = wave * 64;
    const int rA = n & 7;

    f32x4 acc[4];
    #pragma unroll
    for (int cf = 0; cf < 4; ++cf) { acc[cf][0]=0.f; acc[cf][1]=0.f; acc[cf][2]=0.f; acc[cf][3]=0.f; }

    #pragma unroll
    for (int kk = 0; kk < 8; ++kk) {
        short8 ah = *(const short8*)&Ahi[rA][kk*32 + quad*8];
        short8 al = *(const short8*)&Alo[rA][kk*32 + quad*8];
        #pragma unroll
        for (int cf = 0; cf < 4; ++cf) {
            const int o = ow + cf*16 + n;
            short8 bh = *(const short8*)(Wohi + o*EDIM + kk*32 + quad*8);
            short8 bl = *(const short8*)(Wolo + o*EDIM + kk*32 + quad*8);
            acc[cf] = __builtin_amdgcn_mfma_f32_16x16x32_bf16(al, bh, acc[cf], 0, 0, 0);
            acc[cf] = __builtin_amdgcn_mfma_f32_16x16x32_bf16(ah, bl, acc[cf], 0, 0, 0);
            acc[cf] = __builtin_amdgcn_mfma_f32_16x16x32_bf16(ah, bh, acc[cf], 0, 0, 0);
        }
    }

    if (quad < 2) {   // valid rows 0..7
        #pragma unroll
        for (int cf = 0; cf < 4; ++cf) {
            const int o = ow + cf*16 + n;
            const float b = bo[o];
            #pragma unroll
            for (int i = 0; i < 4; ++i) {
                const int row = n0 + 4*quad + i;
                out[row*EDIM + o] = acc[cf][i] + b;
            }
        }
    }
}

// ---------------------------------------------------------------------------
extern "C" void kernel_launch(void* const* d_in, const int* in_sizes, int n_in,
                              void* d_out, int out_size, void* d_ws, size_t ws_size,
                              hipStream_t stream) {
    const float* V   = (const float*)d_in[0];
    const float* K   = (const float*)d_in[1];
    const float* Q   = (const float*)d_in[2];
    const float* pos = (const float*)d_in[3];
    const float* Wq  = (const float*)d_in[4];
    const float* Wk  = (const float*)d_in[5];
    const float* Wv  = (const float*)d_in[6];
    const float* Wr  = (const float*)d_in[7];
    const float* Wo  = (const float*)d_in[8];
    const float* bo  = (const float*)d_in[9];
    float* out = (float*)d_out;
    char* base = (char*)d_ws;

    auto need = [](int P) -> size_t { return 3440640 + (size_t)P * 1114112; };
    int P = 2;
    if (ws_size >= need(8)) P = 8;
    else if (ws_size >= need(4)) P = 4;

    short* qThi  = (short*)(base);
    short* qTlo  = (short*)(base + 524288);
    short* kThi  = (short*)(base + 1048576);
    short* kTlo  = (short*)(base + 1572864);
    short* vThi  = (short*)(base + 2097152);
    short* vTlo  = (short*)(base + 2621440);
    float* coeff = (float*)(base + 3145728);
    short* Wohi  = (short*)(base + 3178496);
    short* Wolo  = (short*)(base + 3309568);
    float* Op    = (float*)(base + 3440640);
    float* Mp    = Op + (size_t)P * 262144;
    float* Lp    = Mp + (size_t)P * 8192;

    proj_kernel  <<<dim3(32, 8, 4), 256, 0, stream>>>(Q, K, V, Wq, Wk, Wv, Wr, Wo,
                                                      qThi, qTlo, kThi, kTlo, vThi, vTlo,
                                                      coeff, Wohi, Wolo);
    attn_kernel  <<<dim3(16, 8, P), 256, 0, stream>>>(qThi, qTlo, kThi, kTlo, vThi, vTlo,
                                                      coeff, pos, Op, Mp, Lp, 16 / P);
    finale_kernel<<<dim3(128),      256, 0, stream>>>(Op, Mp, Lp, Wohi, Wolo, bo, P, out);
}

// Round 5
// 104.605 us; speedup vs baseline: 1.0501x; 1.0501x over previous
//
#include <hip/hip_runtime.h>
#include <math.h>

#define EDIM 256
#define LDIM 1024
#define HDIM 8
#define DDIM 32

typedef __attribute__((ext_vector_type(8))) short short8;
typedef __attribute__((ext_vector_type(4))) short shortx4;
typedef __attribute__((ext_vector_type(4))) float f32x4;

__device__ inline unsigned short bf16h(float x) {
    unsigned u = __float_as_uint(x);
    return (unsigned short)((u + 0x7fff + ((u >> 16) & 1)) >> 16);   // RNE
}
__device__ inline float bf16tof(unsigned short h) {
    return __uint_as_float(((unsigned)h) << 16);
}
// native base-2 transcendentals (v_exp_f32: D=2^S0, v_log_f32: D=log2(S0)).
// Inline asm avoids the glibc __exp2f/__log2f reserved-identifier collision.
__device__ inline float exp2fast(float x) {
    float r; asm volatile("v_exp_f32 %0, %1" : "=v"(r) : "v"(x)); return r;
}
__device__ inline float log2fast(float x) {
    float r; asm volatile("v_log_f32 %0, %1" : "=v"(r) : "v"(x)); return r;
}

// base-2 softmax scale: 1/16 (energy/sqrt(E)) * log2(e)
#define SC2 0.09016843880556021f

// ---------------------------------------------------------------------------
// proj_kernel (MFMA): z<3: dst(H,L,D) = X(L,E) @ W(E,E)^T, outputs written as
// SEPARATE hi/lo bf16 short arrays (consumers do zero unpack ALU). 32x32
// tile, 4 waves x one 16x16 frag, BK=64, split-bf16 3-term. z==0 also fuses
// coeff[h][n] = sum_d q[n,h,d]*Wr[h*32+d]. z==3: split Wo into Wohi/Wolo
// for the outproj kernel (one elem per thread, 256 blocks).
// ---------------------------------------------------------------------------
__global__ __launch_bounds__(256) void proj_kernel(
    const float* __restrict__ Q, const float* __restrict__ Km, const float* __restrict__ V,
    const float* __restrict__ Wq, const float* __restrict__ Wk, const float* __restrict__ Wv,
    const float* __restrict__ Wr, const float* __restrict__ Wo,
    short* __restrict__ qThi, short* __restrict__ qTlo,
    short* __restrict__ kThi, short* __restrict__ kTlo,
    short* __restrict__ vThi, short* __restrict__ vTlo,
    float* __restrict__ coeff, short* __restrict__ Wohi, short* __restrict__ Wolo)
{
    const int z = blockIdx.z;
    const int tid = threadIdx.x;

    if (z == 3) {   // Wo hi/lo split prep (256 blocks x 256 thr = 65536 elems)
        const int idx = ((blockIdx.y * 32 + blockIdx.x) << 8) + tid;
        const float w = Wo[idx];
        const unsigned short hh = bf16h(w);
        Wohi[idx] = (short)hh;
        Wolo[idx] = (short)bf16h(w - bf16tof(hh));
        return;
    }

    const float* __restrict__ X = (z == 0) ? Q : (z == 1) ? Km : V;
    const float* __restrict__ W = (z == 0) ? Wq : (z == 1) ? Wk : Wv;
    short* __restrict__ dhi     = (z == 0) ? qThi : (z == 1) ? kThi : vThi;
    short* __restrict__ dlo     = (z == 0) ? qTlo : (z == 1) ? kTlo : vTlo;

    const int n0 = blockIdx.x * 32;
    const int o0 = blockIdx.y * 32;   // one head: o0 = h*32
    const int wave = tid >> 6, lane = tid & 63;
    const int n = lane & 15, quad = lane >> 4;
    const int rh = wave & 1, oh = wave >> 1;   // wave's row-half / col-half

    // staging role: K-slice s (32 wide), row r (0..31), k-quad qd (8 elems)
    const int s    = tid >> 7;
    const int r    = (tid >> 2) & 31;
    const int qd   = tid & 3;
    const int half = r >> 4;
    const int fl8  = ((r & 15) | (qd << 4)) * 8;   // frag-lane * 8

    __shared__ short Xhi[2][2][512], Xlo[2][2][512];   // [slice][row-half][lane*8]
    __shared__ short Whi[2][2][512], Wlo[2][2][512];
    __shared__ float cpart[2][2][16];

    const float* xp = X + (n0 + r) * EDIM + s * 32 + qd * 8;
    const float* wp = W + (o0 + r) * EDIM + s * 32 + qd * 8;

    float4 xa0 = *(const float4*)xp, xa1 = *(const float4*)(xp + 4);
    float4 wa0 = *(const float4*)wp, wa1 = *(const float4*)(wp + 4);

    f32x4 acc = {0.f, 0.f, 0.f, 0.f};

    for (int kb = 0; kb < EDIM; kb += 64) {
        __syncthreads();   // previous compute done, LDS free
        {
            float xv[8] = {xa0.x,xa0.y,xa0.z,xa0.w, xa1.x,xa1.y,xa1.z,xa1.w};
            float wv[8] = {wa0.x,wa0.y,wa0.z,wa0.w, wa1.x,wa1.y,wa1.z,wa1.w};
            short8 xh, xl, wh, wl;
            #pragma unroll
            for (int j = 0; j < 8; ++j) {
                unsigned short xhh = bf16h(xv[j]);
                unsigned short whh = bf16h(wv[j]);
                xh[j] = (short)xhh; xl[j] = (short)bf16h(xv[j] - bf16tof(xhh));
                wh[j] = (short)whh; wl[j] = (short)bf16h(wv[j] - bf16tof(whh));
            }
            *(short8*)&Xhi[s][half][fl8] = xh;
            *(short8*)&Xlo[s][half][fl8] = xl;
            *(short8*)&Whi[s][half][fl8] = wh;
            *(short8*)&Wlo[s][half][fl8] = wl;
        }
        float4 xn0, xn1, wn0, wn1;
        if (kb + 64 < EDIM) {
            xn0 = *(const float4*)(xp + kb + 64); xn1 = *(const float4*)(xp + kb + 68);
            wn0 = *(const float4*)(wp + kb + 64); wn1 = *(const float4*)(wp + kb + 68);
        }
        __syncthreads();   // staged
        #pragma unroll
        for (int ss = 0; ss < 2; ++ss) {
            short8 ah = *(const short8*)&Xhi[ss][rh][lane*8];
            short8 al = *(const short8*)&Xlo[ss][rh][lane*8];
            short8 bh = *(const short8*)&Whi[ss][oh][lane*8];
            short8 bl = *(const short8*)&Wlo[ss][oh][lane*8];
            acc = __builtin_amdgcn_mfma_f32_16x16x32_bf16(al, bh, acc, 0, 0, 0);
            acc = __builtin_amdgcn_mfma_f32_16x16x32_bf16(ah, bl, acc, 0, 0, 0);
            acc = __builtin_amdgcn_mfma_f32_16x16x32_bf16(ah, bh, acc, 0, 0, 0);
        }
        xa0 = xn0; xa1 = xn1; wa0 = wn0; wa1 = wn1;
    }

    // epilogue: D layout row = rh*16 + 4*quad + i, col = oh*16 + n.
    const int h  = o0 >> 5;
    const int og = oh * 16 + n;
    #pragma unroll
    for (int i = 0; i < 4; ++i) {
        const int row = rh * 16 + 4 * quad + i;
        const unsigned short hh = bf16h(acc[i]);
        dhi[(h * LDIM + n0 + row) * DDIM + og] = (short)hh;
        dlo[(h * LDIM + n0 + row) * DDIM + og] = (short)bf16h(acc[i] - bf16tof(hh));
    }

    if (z == 0) {   // coeff[h][n] = sum over d (all 32 cols = 2 waves x 16 lanes)
        const float wr = Wr[o0 + og];
        #pragma unroll
        for (int i = 0; i < 4; ++i) {
            float c = acc[i] * wr;
            c += __shfl_xor(c, 1, 64);
            c += __shfl_xor(c, 2, 64);
            c += __shfl_xor(c, 4, 64);
            c += __shfl_xor(c, 8, 64);
            if (n == 0) cpart[rh][oh][4*quad + i] = c;
        }
        __syncthreads();
        if (tid < 32)
            coeff[h * LDIM + n0 + tid] = cpart[tid >> 4][0][tid & 15]
                                       + cpart[tid >> 4][1][tid & 15];
    }
}

// ---------------------------------------------------------------------------
// attn_kernel: flash attention, QK^T and PV on MFMA (split-bf16 3-term).
// All operands arrive/live as SEPARATE hi/lo short arrays: K staging is a
// register passthrough (0 ALU), V/P LDS reads are direct short8 frags.
// Softmax is base-2 (v_exp_f32/v_log_f32 natively compute 2^x/log2; log2e
// folded into SC2; cq's ln2 factors cancel exactly). 2 barriers/tile,
// in-register alpha rescale. Block: 64 q-rows, 4 waves. Grid (16, H, P).
// ---------------------------------------------------------------------------
__global__ __launch_bounds__(256, 4) void attn_kernel(
    const short* __restrict__ qThi, const short* __restrict__ qTlo,
    const short* __restrict__ kThi, const short* __restrict__ kTlo,
    const short* __restrict__ vThi, const short* __restrict__ vTlo,
    const float* __restrict__ coeff, const float* __restrict__ pos,
    float* __restrict__ Op, float* __restrict__ Mp, float* __restrict__ Lp, int nkt)
{
    const int h   = blockIdx.y;
    const int q0  = blockIdx.x * 64;
    const int p   = blockIdx.z;
    const int kt0 = p * nkt * 64;
    const int tid  = threadIdx.x;
    const int wave = tid >> 6;
    const int lane = tid & 63;
    const int n    = lane & 15;
    const int quad = lane >> 4;
    const int qs0  = wave * 16;

    __shared__ __align__(16) short khi[4*64*8];      // QK^T B-frags (hi)
    __shared__ __align__(16) short klo[4*64*8];      // QK^T B-frags (lo)
    __shared__ __align__(16) short vs_hi[32][72];    // vs[d][c] (pitch 144B: 16B-aligned rows)
    __shared__ __align__(16) short vs_lo[32][72];
    __shared__ __align__(16) short pa_hi[64][72];    // P[q][c]
    __shared__ __align__(16) short pa_lo[64][72];
    __shared__ float pk[64];

    // ---- Q fragments (A layout): direct short8 loads, zero unpack ----
    const short8 qhi = *(const short8*)(qThi + (h*LDIM + q0 + qs0 + n) * DDIM + quad*8);
    const short8 qlo = *(const short8*)(qTlo + (h*LDIM + q0 + qs0 + n) * DDIM + quad*8);

    float pq[4], cq[4];
    #pragma unroll
    for (int i = 0; i < 4; ++i) {
        const int r = q0 + qs0 + 4*quad + i;
        pq[i] = pos[r];
        cq[i] = coeff[h*LDIM + r] * 0.0625f;
    }

    float m[4], l[4];
    #pragma unroll
    for (int i = 0; i < 4; ++i) { m[i] = -INFINITY; l[i] = 0.f; }

    // O accumulators in MFMA C/D layout: row = 4*quad+i, col d = dt*16 + n
    f32x4 of0 = {0.f,0.f,0.f,0.f}, of1 = {0.f,0.f,0.f,0.f};

    const int cS = tid >> 2;           // k-row 0..63
    const int dq = tid & 3;            // d-chunk 0..3 (8 elems each)
    const int lane2 = (cS & 15) | (dq << 4);
    const int gS = cS >> 4;

    // preload tile 0
    short8 khi_c, klo_c, vhi_c, vlo_c; float pkc = 0.f;
    {
        const int off = (h*LDIM + kt0 + cS) * DDIM + dq*8;
        khi_c = *(const short8*)(kThi + off);
        klo_c = *(const short8*)(kTlo + off);
        vhi_c = *(const short8*)(vThi + off);
        vlo_c = *(const short8*)(vTlo + off);
        if (tid < 64) pkc = pos[kt0 + tid];
    }

    for (int t = 0; t < nkt; ++t) {
        __syncthreads();   // (A) prev tile's consumers done

        // stage K (register passthrough), V (transpose scatter), pk
        *((short8*)&khi[(gS*64 + lane2)*8]) = khi_c;
        *((short8*)&klo[(gS*64 + lane2)*8]) = klo_c;
        #pragma unroll
        for (int j = 0; j < 8; ++j) {
            vs_hi[dq*8 + j][cS] = vhi_c[j];
            vs_lo[dq*8 + j][cS] = vlo_c[j];
        }
        if (tid < 64) pk[tid] = pkc;

        // prefetch next tile (overlaps with compute below)
        short8 khi_n, klo_n, vhi_n, vlo_n; float pkn = 0.f;
        if (t + 1 < nkt) {
            const int off = (h*LDIM + kt0 + (t+1)*64 + cS) * DDIM + dq*8;
            khi_n = *(const short8*)(kThi + off);
            klo_n = *(const short8*)(kTlo + off);
            vhi_n = *(const short8*)(vThi + off);
            vlo_n = *(const short8*)(vTlo + off);
            if (tid < 64) pkn = pos[kt0 + (t+1)*64 + tid];
        }
        __syncthreads();   // (B) staging visible

        // ---- S = QK^T via 3-term split-bf16 MFMA, 4 col-tiles ----
        f32x4 Sf[4];
        #pragma unroll
        for (int t4 = 0; t4 < 4; ++t4) {
            short8 bhi = *((const short8*)&khi[(t4*64 + lane)*8]);
            short8 blo = *((const short8*)&klo[(t4*64 + lane)*8]);
            f32x4 acc = {0.f, 0.f, 0.f, 0.f};
            acc = __builtin_amdgcn_mfma_f32_16x16x32_bf16(qlo, bhi, acc, 0, 0, 0);
            acc = __builtin_amdgcn_mfma_f32_16x16x32_bf16(qhi, blo, acc, 0, 0, 0);
            acc = __builtin_amdgcn_mfma_f32_16x16x32_bf16(qhi, bhi, acc, 0, 0, 0);
            Sf[t4] = acc;
        }

        // ---- bias + online softmax, base-2 domain ----
        float ev[4][4];
        float rmax[4] = {-INFINITY, -INFINITY, -INFINITY, -INFINITY};
        #pragma unroll
        for (int t4 = 0; t4 < 4; ++t4) {
            const float pkt = pk[16*t4 + n];
            #pragma unroll
            for (int i = 0; i < 4; ++i) {
                float s = fmaf(Sf[t4][i], SC2, cq[i] * log2fast(fabsf(pq[i] - pkt) + 1.f));
                ev[t4][i] = s;
                rmax[i] = fmaxf(rmax[i], s);
            }
        }
        #pragma unroll
        for (int off = 1; off < 16; off <<= 1)
            #pragma unroll
            for (int i = 0; i < 4; ++i)
                rmax[i] = fmaxf(rmax[i], __shfl_xor(rmax[i], off, 64));

        float al[4], rsum[4];
        #pragma unroll
        for (int i = 0; i < 4; ++i) {
            const float mn = fmaxf(m[i], rmax[i]);
            al[i] = exp2fast(m[i] - mn);
            m[i] = mn;
            rsum[i] = 0.f;
        }
        // exp2, row-sum, write split P (wave-private rows: no barrier needed)
        #pragma unroll
        for (int t4 = 0; t4 < 4; ++t4)
            #pragma unroll
            for (int i = 0; i < 4; ++i) {
                float e = exp2fast(ev[t4][i] - m[i]);
                rsum[i] += e;
                unsigned u = __float_as_uint(e);
                pa_hi[qs0 + 4*quad + i][16*t4 + n] = (short)(u >> 16);
                float r = e - __uint_as_float(u & 0xffff0000u);
                pa_lo[qs0 + 4*quad + i][16*t4 + n] = (short)bf16h(r);
            }
        #pragma unroll
        for (int off = 1; off < 16; off <<= 1)
            #pragma unroll
            for (int i = 0; i < 4; ++i)
                rsum[i] += __shfl_xor(rsum[i], off, 64);
        #pragma unroll
        for (int i = 0; i < 4; ++i) l[i] = l[i]*al[i] + rsum[i];

        // in-register O rescale: O rows (4*quad+i) match al[i] rows exactly
        #pragma unroll
        for (int i = 0; i < 4; ++i) { of0[i] *= al[i]; of1[i] *= al[i]; }

        // ---- PV on MFMA: direct short8 frag reads, zero unpack ----
        #pragma unroll
        for (int ch = 0; ch < 2; ++ch) {
            short8 phi = *(const short8*)&pa_hi[qs0 + n][ch*32 + quad*8];
            short8 plo = *(const short8*)&pa_lo[qs0 + n][ch*32 + quad*8];
            #pragma unroll
            for (int dt = 0; dt < 2; ++dt) {
                short8 vh8 = *(const short8*)&vs_hi[dt*16 + n][ch*32 + quad*8];
                short8 vl8 = *(const short8*)&vs_lo[dt*16 + n][ch*32 + quad*8];
                f32x4& of = dt ? of1 : of0;   // dt is unroll-constant: static
                of = __builtin_amdgcn_mfma_f32_16x16x32_bf16(plo, vh8, of, 0, 0, 0);
                of = __builtin_amdgcn_mfma_f32_16x16x32_bf16(phi, vl8, of, 0, 0, 0);
                of = __builtin_amdgcn_mfma_f32_16x16x32_bf16(phi, vh8, of, 0, 0, 0);
            }
        }

        khi_c = khi_n; klo_c = klo_n; vhi_c = vhi_n; vlo_c = vlo_n; pkc = pkn;
    }

    // epilogue: O is in C/D layout (row 4*quad+i, col dt*16+n)
    const int ph = p * HDIM + h;
    {
        const size_t base = ((size_t)ph * LDIM + q0 + qs0) * DDIM;
        #pragma unroll
        for (int i = 0; i < 4; ++i) {
            Op[base + (size_t)(4*quad + i)*DDIM + n]      = of0[i];
            Op[base + (size_t)(4*quad + i)*DDIM + 16 + n] = of1[i];
        }
    }
    if (n == 0) {
        #pragma unroll
        for (int i = 0; i < 4; ++i) {
            const int r = q0 + qs0 + 4*quad + i;
            Mp[ph*LDIM + r] = m[i];   // base-2 max
            Lp[ph*LDIM + r] = l[i];
        }
    }
}

// ---------------------------------------------------------------------------
// combine_kernel: A(L,E) = normalized combine of P attention partials,
// written directly as SEPARATE hi/lo bf16 short arrays (halves the write
// bytes vs fp32 and lets outproj stage by pure copy). 256 blocks x 256 thr,
// one float4-worth of A per thread. Mp/Lp loads wave-broadcast.
// ---------------------------------------------------------------------------
__global__ __launch_bounds__(256) void combine_kernel(
    const float* __restrict__ Op, const float* __restrict__ Mp, const float* __restrict__ Lp,
    int P, short* __restrict__ Ahi, short* __restrict__ Alo)
{
    const int idx = blockIdx.x * 256 + threadIdx.x;   // 0..65535
    const int n  = idx >> 6;          // row 0..1023
    const int e4 = (idx & 63) * 4;    // 0..252
    const int h  = e4 >> 5;
    const int d  = e4 & 31;

    float mv[8], lv[8];
    float mx = -INFINITY;
    #pragma unroll
    for (int p = 0; p < 8; ++p) if (p < P) {
        mv[p] = Mp[(p*HDIM + h)*LDIM + n];
        lv[p] = Lp[(p*HDIM + h)*LDIM + n];
        mx = fmaxf(mx, mv[p]);
    }
    float s = 0.f;
    #pragma unroll
    for (int p = 0; p < 8; ++p) if (p < P) {
        float a = exp2fast(mv[p] - mx);   // base-2 m's
        mv[p] = a;
        s += a * lv[p];
    }
    const float inv = 1.f / s;

    float4 x; x.x = x.y = x.z = x.w = 0.f;
    #pragma unroll
    for (int p = 0; p < 8; ++p) if (p < P) {
        const float sp = mv[p] * inv;
        float4 xp = *(const float4*)(Op + ((size_t)(p*HDIM + h)*LDIM + n)*DDIM + d);
        x.x += sp*xp.x; x.y += sp*xp.y; x.z += sp*xp.z; x.w += sp*xp.w;
    }
    float a4[4] = {x.x, x.y, x.z, x.w};
    shortx4 ah4, al4;
    #pragma unroll
    for (int j = 0; j < 4; ++j) {
        const unsigned short hh = bf16h(a4[j]);
        ah4[j] = (short)hh;
        al4[j] = (short)bf16h(a4[j] - bf16tof(hh));
    }
    *(shortx4*)(Ahi + n*EDIM + e4) = ah4;
    *(shortx4*)(Alo + n*EDIM + e4) = al4;
}

// ---------------------------------------------------------------------------
// outproj_kernel (MFMA): out(L,E) = A(L,E) @ Wo(E,E)^T + bo. A and Wo are
// both PRE-SPLIT hi/lo short arrays -> LDS staging is a pure copy (zero
// conversion ALU). 32x32 tiles, 4 waves x one 16x16 frag, BK=64, 3-term,
// grid (32,8)=256 blocks, software-pipelined.
// ---------------------------------------------------------------------------
__global__ __launch_bounds__(256) void outproj_kernel(
    const short* __restrict__ Ahi, const short* __restrict__ Alo,
    const short* __restrict__ Wohi, const short* __restrict__ Wolo,
    const float* __restrict__ bo, float* __restrict__ out)
{
    const int n0 = blockIdx.x * 32;
    const int o0 = blockIdx.y * 32;
    const int tid = threadIdx.x;
    const int wave = tid >> 6, lane = tid & 63;
    const int n = lane & 15, quad = lane >> 4;
    const int rh = wave & 1, oh = wave >> 1;

    const int s    = tid >> 7;
    const int r    = (tid >> 2) & 31;
    const int qd   = tid & 3;
    const int half = r >> 4;
    const int fl8  = ((r & 15) | (qd << 4)) * 8;

    __shared__ short Xhi[2][2][512], Xlo[2][2][512];
    __shared__ short Whi[2][2][512], Wlo[2][2][512];

    const short* xph = Ahi  + (n0 + r) * EDIM + s * 32 + qd * 8;
    const short* xpl = Alo  + (n0 + r) * EDIM + s * 32 + qd * 8;
    const short* wph = Wohi + (o0 + r) * EDIM + s * 32 + qd * 8;
    const short* wpl = Wolo + (o0 + r) * EDIM + s * 32 + qd * 8;

    short8 xh_c = *(const short8*)xph;
    short8 xl_c = *(const short8*)xpl;
    short8 wh_c = *(const short8*)wph;
    short8 wl_c = *(const short8*)wpl;

    f32x4 acc = {0.f, 0.f, 0.f, 0.f};

    for (int kb = 0; kb < EDIM; kb += 64) {
        __syncthreads();   // previous compute done, LDS free
        *(short8*)&Xhi[s][half][fl8] = xh_c;
        *(short8*)&Xlo[s][half][fl8] = xl_c;
        *(short8*)&Whi[s][half][fl8] = wh_c;
        *(short8*)&Wlo[s][half][fl8] = wl_c;
        short8 xh_n, xl_n, wh_n, wl_n;
        if (kb + 64 < EDIM) {
            xh_n = *(const short8*)(xph + kb + 64);
            xl_n = *(const short8*)(xpl + kb + 64);
            wh_n = *(const short8*)(wph + kb + 64);
            wl_n = *(const short8*)(wpl + kb + 64);
        }
        __syncthreads();   // staged
        #pragma unroll
        for (int ss = 0; ss < 2; ++ss) {
            short8 ah = *(const short8*)&Xhi[ss][rh][lane*8];
            short8 al = *(const short8*)&Xlo[ss][rh][lane*8];
            short8 bh = *(const short8*)&Whi[ss][oh][lane*8];
            short8 bl = *(const short8*)&Wlo[ss][oh][lane*8];
            acc = __builtin_amdgcn_mfma_f32_16x16x32_bf16(al, bh, acc, 0, 0, 0);
            acc = __builtin_amdgcn_mfma_f32_16x16x32_bf16(ah, bl, acc, 0, 0, 0);
            acc = __builtin_amdgcn_mfma_f32_16x16x32_bf16(ah, bh, acc, 0, 0, 0);
        }
        xh_c = xh_n; xl_c = xl_n; wh_c = wh_n; wl_c = wl_n;
    }

    const int og = o0 + oh*16 + n;
    const float b = bo[og];
    #pragma unroll
    for (int i = 0; i < 4; ++i) {
        const int row = n0 + rh*16 + 4*quad + i;
        out[row * EDIM + og] = acc[i] + b;
    }
}

// ---------------------------------------------------------------------------
extern "C" void kernel_launch(void* const* d_in, const int* in_sizes, int n_in,
                              void* d_out, int out_size, void* d_ws, size_t ws_size,
                              hipStream_t stream) {
    const float* V   = (const float*)d_in[0];
    const float* K   = (const float*)d_in[1];
    const float* Q   = (const float*)d_in[2];
    const float* pos = (const float*)d_in[3];
    const float* Wq  = (const float*)d_in[4];
    const float* Wk  = (const float*)d_in[5];
    const float* Wv  = (const float*)d_in[6];
    const float* Wr  = (const float*)d_in[7];
    const float* Wo  = (const float*)d_in[8];
    const float* bo  = (const float*)d_in[9];
    float* out = (float*)d_out;
    char* base = (char*)d_ws;

    auto need = [](int P) -> size_t { return 3440640 + (size_t)P * 1114112; };
    int P = 2;
    if (ws_size >= need(8)) P = 8;
    else if (ws_size >= need(4)) P = 4;

    short* qThi  = (short*)(base);
    short* qTlo  = (short*)(base + 524288);
    short* kThi  = (short*)(base + 1048576);
    short* kTlo  = (short*)(base + 1572864);
    short* vThi  = (short*)(base + 2097152);
    short* vTlo  = (short*)(base + 2621440);
    float* coeff = (float*)(base + 3145728);
    short* Wohi  = (short*)(base + 3178496);
    short* Wolo  = (short*)(base + 3309568);
    float* Op    = (float*)(base + 3440640);
    float* Mp    = Op + (size_t)P * 262144;
    float* Lp    = Mp + (size_t)P * 8192;
    short* Ahi   = qThi;   // qT dead after attn_kernel
    short* Alo   = qTlo;

    proj_kernel   <<<dim3(32, 8, 4), 256, 0, stream>>>(Q, K, V, Wq, Wk, Wv, Wr, Wo,
                                                       qThi, qTlo, kThi, kTlo, vThi, vTlo,
                                                       coeff, Wohi, Wolo);
    attn_kernel   <<<dim3(16, 8, P), 256, 0, stream>>>(qThi, qTlo, kThi, kTlo, vThi, vTlo,
                                                       coeff, pos, Op, Mp, Lp, 16 / P);
    combine_kernel<<<dim3(256),      256, 0, stream>>>(Op, Mp, Lp, P, Ahi, Alo);
    outproj_kernel<<<dim3(32, 8),    256, 0, stream>>>(Ahi, Alo, Wohi, Wolo, bo, out);
}

// Round 6
// 100.770 us; speedup vs baseline: 1.0900x; 1.0381x over previous
//
#include <hip/hip_runtime.h>
#include <math.h>

#define EDIM 256
#define LDIM 1024
#define HDIM 8
#define DDIM 32

typedef __attribute__((ext_vector_type(8))) short short8;
typedef __attribute__((ext_vector_type(2))) short short2v;
typedef __attribute__((ext_vector_type(4))) short shortx4;
typedef __attribute__((ext_vector_type(4))) float f32x4;

__device__ inline unsigned short bf16h(float x) {
    unsigned u = __float_as_uint(x);
    return (unsigned short)((u + 0x7fff + ((u >> 16) & 1)) >> 16);   // RNE
}
__device__ inline float bf16tof(unsigned short h) {
    return __uint_as_float(((unsigned)h) << 16);
}
// native base-2 transcendentals (v_exp_f32: D=2^S0, v_log_f32: D=log2(S0)).
// Inline asm avoids the glibc __exp2f/__log2f reserved-identifier collision.
__device__ inline float exp2fast(float x) {
    float r; asm volatile("v_exp_f32 %0, %1" : "=v"(r) : "v"(x)); return r;
}
__device__ inline float log2fast(float x) {
    float r; asm volatile("v_log_f32 %0, %1" : "=v"(r) : "v"(x)); return r;
}

// base-2 softmax scale: 1/16 (energy/sqrt(E)) * log2(e)
#define SC2 0.09016843880556021f

// ---------------------------------------------------------------------------
// proj_kernel (MFMA): z<3: dst(H,L,D) = X(L,E) @ W(E,E)^T, outputs written as
// SEPARATE hi/lo bf16 short arrays (consumers do zero unpack ALU). 32x32
// tile, 4 waves x one 16x16 frag, BK=64, split-bf16 3-term. z==0 also fuses
// coeff[h][n] = sum_d q[n,h,d]*Wr[h*32+d]. z==3: split Wo into Wohi/Wolo
// for the outproj kernel (one elem per thread, 256 blocks).
// ---------------------------------------------------------------------------
__global__ __launch_bounds__(256) void proj_kernel(
    const float* __restrict__ Q, const float* __restrict__ Km, const float* __restrict__ V,
    const float* __restrict__ Wq, const float* __restrict__ Wk, const float* __restrict__ Wv,
    const float* __restrict__ Wr, const float* __restrict__ Wo,
    short* __restrict__ qThi, short* __restrict__ qTlo,
    short* __restrict__ kThi, short* __restrict__ kTlo,
    short* __restrict__ vThi, short* __restrict__ vTlo,
    float* __restrict__ coeff, short* __restrict__ Wohi, short* __restrict__ Wolo)
{
    const int z = blockIdx.z;
    const int tid = threadIdx.x;

    if (z == 3) {   // Wo hi/lo split prep (256 blocks x 256 thr = 65536 elems)
        const int idx = ((blockIdx.y * 32 + blockIdx.x) << 8) + tid;
        const float w = Wo[idx];
        const unsigned short hh = bf16h(w);
        Wohi[idx] = (short)hh;
        Wolo[idx] = (short)bf16h(w - bf16tof(hh));
        return;
    }

    const float* __restrict__ X = (z == 0) ? Q : (z == 1) ? Km : V;
    const float* __restrict__ W = (z == 0) ? Wq : (z == 1) ? Wk : Wv;
    short* __restrict__ dhi     = (z == 0) ? qThi : (z == 1) ? kThi : vThi;
    short* __restrict__ dlo     = (z == 0) ? qTlo : (z == 1) ? kTlo : vTlo;

    const int n0 = blockIdx.x * 32;
    const int o0 = blockIdx.y * 32;   // one head: o0 = h*32
    const int wave = tid >> 6, lane = tid & 63;
    const int n = lane & 15, quad = lane >> 4;
    const int rh = wave & 1, oh = wave >> 1;   // wave's row-half / col-half

    // staging role: K-slice s (32 wide), row r (0..31), k-quad qd (8 elems)
    const int s    = tid >> 7;
    const int r    = (tid >> 2) & 31;
    const int qd   = tid & 3;
    const int half = r >> 4;
    const int fl8  = ((r & 15) | (qd << 4)) * 8;   // frag-lane * 8

    __shared__ short Xhi[2][2][512], Xlo[2][2][512];   // [slice][row-half][lane*8]
    __shared__ short Whi[2][2][512], Wlo[2][2][512];
    __shared__ float cpart[2][2][16];

    const float* xp = X + (n0 + r) * EDIM + s * 32 + qd * 8;
    const float* wp = W + (o0 + r) * EDIM + s * 32 + qd * 8;

    float4 xa0 = *(const float4*)xp, xa1 = *(const float4*)(xp + 4);
    float4 wa0 = *(const float4*)wp, wa1 = *(const float4*)(wp + 4);

    f32x4 acc = {0.f, 0.f, 0.f, 0.f};

    for (int kb = 0; kb < EDIM; kb += 64) {
        __syncthreads();   // previous compute done, LDS free
        {
            float xv[8] = {xa0.x,xa0.y,xa0.z,xa0.w, xa1.x,xa1.y,xa1.z,xa1.w};
            float wv[8] = {wa0.x,wa0.y,wa0.z,wa0.w, wa1.x,wa1.y,wa1.z,wa1.w};
            short8 xh, xl, wh, wl;
            #pragma unroll
            for (int j = 0; j < 8; ++j) {
                unsigned short xhh = bf16h(xv[j]);
                unsigned short whh = bf16h(wv[j]);
                xh[j] = (short)xhh; xl[j] = (short)bf16h(xv[j] - bf16tof(xhh));
                wh[j] = (short)whh; wl[j] = (short)bf16h(wv[j] - bf16tof(whh));
            }
            *(short8*)&Xhi[s][half][fl8] = xh;
            *(short8*)&Xlo[s][half][fl8] = xl;
            *(short8*)&Whi[s][half][fl8] = wh;
            *(short8*)&Wlo[s][half][fl8] = wl;
        }
        float4 xn0, xn1, wn0, wn1;
        if (kb + 64 < EDIM) {
            xn0 = *(const float4*)(xp + kb + 64); xn1 = *(const float4*)(xp + kb + 68);
            wn0 = *(const float4*)(wp + kb + 64); wn1 = *(const float4*)(wp + kb + 68);
        }
        __syncthreads();   // staged
        #pragma unroll
        for (int ss = 0; ss < 2; ++ss) {
            short8 ah = *(const short8*)&Xhi[ss][rh][lane*8];
            short8 al = *(const short8*)&Xlo[ss][rh][lane*8];
            short8 bh = *(const short8*)&Whi[ss][oh][lane*8];
            short8 bl = *(const short8*)&Wlo[ss][oh][lane*8];
            acc = __builtin_amdgcn_mfma_f32_16x16x32_bf16(al, bh, acc, 0, 0, 0);
            acc = __builtin_amdgcn_mfma_f32_16x16x32_bf16(ah, bl, acc, 0, 0, 0);
            acc = __builtin_amdgcn_mfma_f32_16x16x32_bf16(ah, bh, acc, 0, 0, 0);
        }
        xa0 = xn0; xa1 = xn1; wa0 = wn0; wa1 = wn1;
    }

    // epilogue: D layout row = rh*16 + 4*quad + i, col = oh*16 + n.
    const int h  = o0 >> 5;
    const int og = oh * 16 + n;
    #pragma unroll
    for (int i = 0; i < 4; ++i) {
        const int row = rh * 16 + 4 * quad + i;
        const unsigned short hh = bf16h(acc[i]);
        dhi[(h * LDIM + n0 + row) * DDIM + og] = (short)hh;
        dlo[(h * LDIM + n0 + row) * DDIM + og] = (short)bf16h(acc[i] - bf16tof(hh));
    }

    if (z == 0) {   // coeff[h][n] = sum over d (all 32 cols = 2 waves x 16 lanes)
        const float wr = Wr[o0 + og];
        #pragma unroll
        for (int i = 0; i < 4; ++i) {
            float c = acc[i] * wr;
            c += __shfl_xor(c, 1, 64);
            c += __shfl_xor(c, 2, 64);
            c += __shfl_xor(c, 4, 64);
            c += __shfl_xor(c, 8, 64);
            if (n == 0) cpart[rh][oh][4*quad + i] = c;
        }
        __syncthreads();
        if (tid < 32)
            coeff[h * LDIM + n0 + tid] = cpart[tid >> 4][0][tid & 15]
                                       + cpart[tid >> 4][1][tid & 15];
    }
}

// ---------------------------------------------------------------------------
// attn_kernel: FULL-K flash attention per block -> no cross-block partials,
// no combine kernel, no Op/Mp/Lp traffic. Grid (64,8) = 512 blocks (2/CU):
// 16 q-rows per block, 4 waves; wave w owns k-range [w*256, w*256+256)
// (4 tiles of 64) with its own online softmax. ZERO barriers in the main
// loop: V/P LDS slices are wave-private; K-fragments are read DIRECT from
// global (kThi layout is already fragment-shaped; L2-resident). One
// __syncthreads at the end merges the 4 wave-partials (in-block flash
// combine) and writes normalized A as split hi/lo for outproj.
// ---------------------------------------------------------------------------
__global__ __launch_bounds__(256, 2) void attn_kernel(
    const short* __restrict__ qThi, const short* __restrict__ qTlo,
    const short* __restrict__ kThi, const short* __restrict__ kTlo,
    const short* __restrict__ vThi, const short* __restrict__ vTlo,
    const float* __restrict__ coeff, const float* __restrict__ pos,
    short* __restrict__ Ahi, short* __restrict__ Alo)
{
    const int h    = blockIdx.y;
    const int q0   = blockIdx.x * 16;
    const int tid  = threadIdx.x;
    const int wave = tid >> 6;
    const int lane = tid & 63;
    const int n    = lane & 15;
    const int quad = lane >> 4;

    __shared__ __align__(16) short vs_hi[4][32][72];   // per-wave V slice [d][krow]
    __shared__ __align__(16) short vs_lo[4][32][72];
    __shared__ __align__(16) short pa_hi[4][16][72];   // per-wave P [q][krow]
    __shared__ __align__(16) short pa_lo[4][16][72];
    __shared__ float mw[4][16], lw[4][16];             // wave-partial m, l
    __shared__ float Ow[4][16][36];                    // wave-partial O

    // ---- Q fragment (same 16 rows for all waves) ----
    const short8 qhi = *(const short8*)(qThi + (h*LDIM + q0 + n) * DDIM + quad*8);
    const short8 qlo = *(const short8*)(qTlo + (h*LDIM + q0 + n) * DDIM + quad*8);

    float pq[4], cq[4];
    #pragma unroll
    for (int i = 0; i < 4; ++i) {
        const int r = q0 + 4*quad + i;
        pq[i] = pos[r];
        cq[i] = coeff[h*LDIM + r] * 0.0625f;
    }

    float m[4], l[4];
    #pragma unroll
    for (int i = 0; i < 4; ++i) { m[i] = -INFINITY; l[i] = 0.f; }
    f32x4 of0 = {0.f,0.f,0.f,0.f}, of1 = {0.f,0.f,0.f,0.f};

    const int ktb = wave * 256;   // this wave's k-range
    #pragma unroll 1
    for (int t = 0; t < 4; ++t) {
        const int kt = ktb + t * 64;

        // ---- stage V: lane stages krow kt+lane (contiguous 64B loads,
        //      2-way-free scalar stores into wave-private slice) ----
        {
            const short* vh = vThi + (h*LDIM + kt + lane) * DDIM;
            const short* vl = vTlo + (h*LDIM + kt + lane) * DDIM;
            #pragma unroll
            for (int hf = 0; hf < 2; ++hf) {
                short8 a0 = *(const short8*)(vh + hf*16);
                short8 a1 = *(const short8*)(vh + hf*16 + 8);
                short8 b0 = *(const short8*)(vl + hf*16);
                short8 b1 = *(const short8*)(vl + hf*16 + 8);
                #pragma unroll
                for (int j = 0; j < 8; ++j) {
                    vs_hi[wave][hf*16 + j][lane]     = a0[j];
                    vs_hi[wave][hf*16 + 8 + j][lane] = a1[j];
                    vs_lo[wave][hf*16 + j][lane]     = b0[j];
                    vs_lo[wave][hf*16 + 8 + j][lane] = b1[j];
                }
            }
        }

        // ---- S = QK^T: K-fragments direct from global (frag-shaped layout) ----
        f32x4 Sf[4];
        #pragma unroll
        for (int t4 = 0; t4 < 4; ++t4) {
            const int off = (h*LDIM + kt + t4*16 + n) * DDIM + quad*8;
            short8 bh = *(const short8*)(kThi + off);
            short8 bl = *(const short8*)(kTlo + off);
            f32x4 acc = {0.f, 0.f, 0.f, 0.f};
            acc = __builtin_amdgcn_mfma_f32_16x16x32_bf16(qlo, bh, acc, 0, 0, 0);
            acc = __builtin_amdgcn_mfma_f32_16x16x32_bf16(qhi, bl, acc, 0, 0, 0);
            acc = __builtin_amdgcn_mfma_f32_16x16x32_bf16(qhi, bh, acc, 0, 0, 0);
            Sf[t4] = acc;
        }

        // ---- bias + online softmax (base-2) ----
        float ev[4][4];
        float rmax[4] = {-INFINITY, -INFINITY, -INFINITY, -INFINITY};
        #pragma unroll
        for (int t4 = 0; t4 < 4; ++t4) {
            const float pkt = pos[kt + t4*16 + n];
            #pragma unroll
            for (int i = 0; i < 4; ++i) {
                float s = fmaf(Sf[t4][i], SC2, cq[i] * log2fast(fabsf(pq[i] - pkt) + 1.f));
                ev[t4][i] = s;
                rmax[i] = fmaxf(rmax[i], s);
            }
        }
        #pragma unroll
        for (int off = 1; off < 16; off <<= 1)
            #pragma unroll
            for (int i = 0; i < 4; ++i)
                rmax[i] = fmaxf(rmax[i], __shfl_xor(rmax[i], off, 64));

        float al[4], rsum[4];
        #pragma unroll
        for (int i = 0; i < 4; ++i) {
            const float mn = fmaxf(m[i], rmax[i]);
            al[i] = exp2fast(m[i] - mn);
            m[i] = mn;
            rsum[i] = 0.f;
        }
        // exp2, row-sum, split-write P into wave-private slice
        #pragma unroll
        for (int t4 = 0; t4 < 4; ++t4)
            #pragma unroll
            for (int i = 0; i < 4; ++i) {
                float e = exp2fast(ev[t4][i] - m[i]);
                rsum[i] += e;
                unsigned u = __float_as_uint(e);
                pa_hi[wave][4*quad + i][16*t4 + n] = (short)(u >> 16);
                float r = e - __uint_as_float(u & 0xffff0000u);
                pa_lo[wave][4*quad + i][16*t4 + n] = (short)bf16h(r);
            }
        #pragma unroll
        for (int off = 1; off < 16; off <<= 1)
            #pragma unroll
            for (int i = 0; i < 4; ++i)
                rsum[i] += __shfl_xor(rsum[i], off, 64);
        #pragma unroll
        for (int i = 0; i < 4; ++i) l[i] = l[i]*al[i] + rsum[i];

        // in-register O rescale (rows 4*quad+i match al rows)
        #pragma unroll
        for (int i = 0; i < 4; ++i) { of0[i] *= al[i]; of1[i] *= al[i]; }

        // ---- PV on MFMA from wave-private LDS ----
        #pragma unroll
        for (int ch = 0; ch < 2; ++ch) {
            short8 phi = *(const short8*)&pa_hi[wave][n][ch*32 + quad*8];
            short8 plo = *(const short8*)&pa_lo[wave][n][ch*32 + quad*8];
            #pragma unroll
            for (int dt = 0; dt < 2; ++dt) {
                short8 vh8 = *(const short8*)&vs_hi[wave][dt*16 + n][ch*32 + quad*8];
                short8 vl8 = *(const short8*)&vs_lo[wave][dt*16 + n][ch*32 + quad*8];
                f32x4& of = dt ? of1 : of0;
                of = __builtin_amdgcn_mfma_f32_16x16x32_bf16(plo, vh8, of, 0, 0, 0);
                of = __builtin_amdgcn_mfma_f32_16x16x32_bf16(phi, vl8, of, 0, 0, 0);
                of = __builtin_amdgcn_mfma_f32_16x16x32_bf16(phi, vh8, of, 0, 0, 0);
            }
        }
    }

    // ---- in-block flash combine of the 4 wave partials ----
    #pragma unroll
    for (int i = 0; i < 4; ++i) {
        Ow[wave][4*quad + i][n]      = of0[i];
        Ow[wave][4*quad + i][16 + n] = of1[i];
    }
    if (n == 0) {
        #pragma unroll
        for (int i = 0; i < 4; ++i) {
            mw[wave][4*quad + i] = m[i];
            lw[wave][4*quad + i] = l[i];
        }
    }
    __syncthreads();   // the only barrier

    {
        const int q  = tid >> 4;          // 0..15
        const int dp = (tid & 15) * 2;    // 0..30
        float M = fmaxf(fmaxf(mw[0][q], mw[1][q]), fmaxf(mw[2][q], mw[3][q]));
        float sc[4], s = 0.f;
        #pragma unroll
        for (int w = 0; w < 4; ++w) {
            sc[w] = exp2fast(mw[w][q] - M);
            s += sc[w] * lw[w][q];
        }
        const float inv = 1.f / s;
        short2v h2, l2;
        #pragma unroll
        for (int e = 0; e < 2; ++e) {
            float a = 0.f;
            #pragma unroll
            for (int w = 0; w < 4; ++w) a += sc[w] * Ow[w][q][dp + e];
            a *= inv;
            const unsigned short hh = bf16h(a);
            h2[e] = (short)hh;
            l2[e] = (short)bf16h(a - bf16tof(hh));
        }
        *(short2v*)(Ahi + (q0 + q)*EDIM + h*DDIM + dp) = h2;
        *(short2v*)(Alo + (q0 + q)*EDIM + h*DDIM + dp) = l2;
    }
}

// ---------------------------------------------------------------------------
// outproj_kernel (MFMA): out(L,E) = A(L,E) @ Wo(E,E)^T + bo. A and Wo are
// both PRE-SPLIT hi/lo short arrays -> LDS staging is a pure copy (zero
// conversion ALU). 32x32 tiles, 4 waves x one 16x16 frag, BK=64, 3-term,
// grid (32,8)=256 blocks, software-pipelined.
// ---------------------------------------------------------------------------
__global__ __launch_bounds__(256) void outproj_kernel(
    const short* __restrict__ Ahi, const short* __restrict__ Alo,
    const short* __restrict__ Wohi, const short* __restrict__ Wolo,
    const float* __restrict__ bo, float* __restrict__ out)
{
    const int n0 = blockIdx.x * 32;
    const int o0 = blockIdx.y * 32;
    const int tid = threadIdx.x;
    const int wave = tid >> 6, lane = tid & 63;
    const int n = lane & 15, quad = lane >> 4;
    const int rh = wave & 1, oh = wave >> 1;

    const int s    = tid >> 7;
    const int r    = (tid >> 2) & 31;
    const int qd   = tid & 3;
    const int half = r >> 4;
    const int fl8  = ((r & 15) | (qd << 4)) * 8;

    __shared__ short Xhi[2][2][512], Xlo[2][2][512];
    __shared__ short Whi[2][2][512], Wlo[2][2][512];

    const short* xph = Ahi  + (n0 + r) * EDIM + s * 32 + qd * 8;
    const short* xpl = Alo  + (n0 + r) * EDIM + s * 32 + qd * 8;
    const short* wph = Wohi + (o0 + r) * EDIM + s * 32 + qd * 8;
    const short* wpl = Wolo + (o0 + r) * EDIM + s * 32 + qd * 8;

    short8 xh_c = *(const short8*)xph;
    short8 xl_c = *(const short8*)xpl;
    short8 wh_c = *(const short8*)wph;
    short8 wl_c = *(const short8*)wpl;

    f32x4 acc = {0.f, 0.f, 0.f, 0.f};

    for (int kb = 0; kb < EDIM; kb += 64) {
        __syncthreads();   // previous compute done, LDS free
        *(short8*)&Xhi[s][half][fl8] = xh_c;
        *(short8*)&Xlo[s][half][fl8] = xl_c;
        *(short8*)&Whi[s][half][fl8] = wh_c;
        *(short8*)&Wlo[s][half][fl8] = wl_c;
        short8 xh_n, xl_n, wh_n, wl_n;
        if (kb + 64 < EDIM) {
            xh_n = *(const short8*)(xph + kb + 64);
            xl_n = *(const short8*)(xpl + kb + 64);
            wh_n = *(const short8*)(wph + kb + 64);
            wl_n = *(const short8*)(wpl + kb + 64);
        }
        __syncthreads();   // staged
        #pragma unroll
        for (int ss = 0; ss < 2; ++ss) {
            short8 ah = *(const short8*)&Xhi[ss][rh][lane*8];
            short8 al = *(const short8*)&Xlo[ss][rh][lane*8];
            short8 bh = *(const short8*)&Whi[ss][oh][lane*8];
            short8 bl = *(const short8*)&Wlo[ss][oh][lane*8];
            acc = __builtin_amdgcn_mfma_f32_16x16x32_bf16(al, bh, acc, 0, 0, 0);
            acc = __builtin_amdgcn_mfma_f32_16x16x32_bf16(ah, bl, acc, 0, 0, 0);
            acc = __builtin_amdgcn_mfma_f32_16x16x32_bf16(ah, bh, acc, 0, 0, 0);
        }
        xh_c = xh_n; xl_c = xl_n; wh_c = wh_n; wl_c = wl_n;
    }

    const int og = o0 + oh*16 + n;
    const float b = bo[og];
    #pragma unroll
    for (int i = 0; i < 4; ++i) {
        const int row = n0 + rh*16 + 4*quad + i;
        out[row * EDIM + og] = acc[i] + b;
    }
}

// ---------------------------------------------------------------------------
extern "C" void kernel_launch(void* const* d_in, const int* in_sizes, int n_in,
                              void* d_out, int out_size, void* d_ws, size_t ws_size,
                              hipStream_t stream) {
    const float* V   = (const float*)d_in[0];
    const float* K   = (const float*)d_in[1];
    const float* Q   = (const float*)d_in[2];
    const float* pos = (const float*)d_in[3];
    const float* Wq  = (const float*)d_in[4];
    const float* Wk  = (const float*)d_in[5];
    const float* Wv  = (const float*)d_in[6];
    const float* Wr  = (const float*)d_in[7];
    const float* Wo  = (const float*)d_in[8];
    const float* bo  = (const float*)d_in[9];
    float* out = (float*)d_out;
    char* base = (char*)d_ws;

    short* qThi  = (short*)(base);
    short* qTlo  = (short*)(base + 524288);
    short* kThi  = (short*)(base + 1048576);
    short* kTlo  = (short*)(base + 1572864);
    short* vThi  = (short*)(base + 2097152);
    short* vTlo  = (short*)(base + 2621440);
    float* coeff = (float*)(base + 3145728);
    short* Wohi  = (short*)(base + 3178496);
    short* Wolo  = (short*)(base + 3309568);
    short* Ahi   = (short*)(base + 3440640);
    short* Alo   = (short*)(base + 3964928);
    // total workspace use: 4489216 bytes (harness provides >= 12 MB)

    proj_kernel   <<<dim3(32, 8, 4), 256, 0, stream>>>(Q, K, V, Wq, Wk, Wv, Wr, Wo,
                                                       qThi, qTlo, kThi, kTlo, vThi, vTlo,
                                                       coeff, Wohi, Wolo);
    attn_kernel   <<<dim3(64, 8),    256, 0, stream>>>(qThi, qTlo, kThi, kTlo, vThi, vTlo,
                                                       coeff, pos, Ahi, Alo);
    outproj_kernel<<<dim3(32, 8),    256, 0, stream>>>(Ahi, Alo, Wohi, Wolo, bo, out);
}